// Round 10
// baseline (51.054 us; speedup 1.0000x reference)
//
#include <hip/hip_runtime.h>
#include <math.h>

#define NFEAT  512
#define NHID   128
#define NCLASS 70
#define NIDX   10000
#define NTILE  625
#define HELEMS (2u * NIDX * NHID)          // 2,560,000 ushorts: H scratch
#define WS_NEED ((size_t)HELEMS * 2)       // ~5.12 MB

typedef float  f32x4  __attribute__((ext_vector_type(4)));
typedef __bf16 bf16x8 __attribute__((ext_vector_type(8)));

static __device__ __forceinline__ unsigned short f2bf(float f) {
    unsigned u = __builtin_bit_cast(unsigned, f);
    u += 0x7fffu + ((u >> 16) & 1u);
    return (unsigned short)(u >> 16);
}
static __device__ __forceinline__ float bf2f(unsigned short h) {
    unsigned u = ((unsigned)h) << 16;
    return __builtin_bit_cast(float, u);
}
static __device__ __forceinline__ bf16x8 pack8(float4 a, float4 b) {
    bf16x8 r;
    r[0] = (__bf16)a.x; r[1] = (__bf16)a.y; r[2] = (__bf16)a.z; r[3] = (__bf16)a.w;
    r[4] = (__bf16)b.x; r[5] = (__bf16)b.y; r[6] = (__bf16)b.z; r[7] = (__bf16)b.w;
    return r;
}
static __device__ __forceinline__ bf16x8 pack8s(float4 a, float4 b, float s) {
    bf16x8 r;
    r[0] = (__bf16)(a.x * s); r[1] = (__bf16)(a.y * s); r[2] = (__bf16)(a.z * s); r[3] = (__bf16)(a.w * s);
    r[4] = (__bf16)(b.x * s); r[5] = (__bf16)(b.y * s); r[6] = (__bf16)(b.z * s); r[7] = (__bf16)(b.w * s);
    return r;
}
static __device__ __forceinline__ f32x4 MFMA(bf16x8 a, bf16x8 b, f32x4 c) {
    return __builtin_amdgcn_mfma_f32_16x16x32_bf16(a, b, c, 0, 0, 0);
}
static __device__ __forceinline__ bf16x8 ldsAx(const unsigned short* base, int row, int colb, int rstride) {
    return *(const bf16x8*)((const char*)base + row * rstride + (colb ^ ((row & 7) << 4)));
}
static __device__ __forceinline__ void ldsW1(unsigned short* base, int row, int col, unsigned short v) {
    *(unsigned short*)((char*)base + row * 256 + ((col * 2) ^ ((row & 7) << 4))) = v;
}
static __device__ __forceinline__ float ldsR1(const unsigned short* base, int row, int col) {
    return bf2f(*(const unsigned short*)((const char*)base + row * 256 + ((col * 2) ^ ((row & 7) << 4))));
}

// ---- kernel 1: weights-stationary stage B; W converted f32->bf16 inline ----
// 250 blocks (2 tensors x 125), 5 tiles each; W image resident in LDS.
__global__ __launch_bounds__(512) void stageB_ws(
    const float* __restrict__ x, const float* __restrict__ sf,
    const int* __restrict__ idx,
    const float* __restrict__ W0, const float* __restrict__ W1,
    unsigned short* __restrict__ wsH)
{
    __shared__ __align__(16) unsigned short Wl[65536];  // 128 KB swizzled W image
    __shared__ __align__(16) unsigned short Xl[8192];   // 16 KB swizzled X tile
    __shared__ __align__(16) unsigned short Hl[2048];   // 4 KB swizzled H tile

    const int tid  = threadIdx.x;
    const int w    = tid >> 6;          // wave 0..7
    const int lane = tid & 63;
    const int ln   = lane & 15, lg = lane >> 4;
    const int bid  = blockIdx.x;
    const int t    = bid / 125, tb = bid % 125;
    const int tile0 = tb * 5;
    const float* XS = t ? sf : x;
    const float* Wsrc = t ? W1 : W0;
    const f32x4 zero4 = {0.f, 0.f, 0.f, 0.f};

    // gather volley for tile 0 (wave w owns rows w and w+8) — longest latency, issue first
    float4 ga0, ga1, gb0, gb1;
    {
        int r0 = idx[tile0 * 16 + w];
        int r1 = idx[tile0 * 16 + w + 8];
        const float4* p0 = (const float4*)(XS + (size_t)r0 * NFEAT + lane * 8);
        const float4* p1 = (const float4*)(XS + (size_t)r1 * NFEAT + lane * 8);
        ga0 = p0[0]; ga1 = p0[1];
        gb0 = p1[0]; gb1 = p1[1];
    }
    // W f32 -> bf16 LDS image, coalesced L2 stream + in-reg pack (overlaps gather)
    #pragma unroll
    for (int j = 0; j < 16; ++j) {
        int i = tid + j * 512;
        int n = i >> 6, k8 = i & 63;
        const float4* q = (const float4*)(Wsrc + (size_t)n * NFEAT + k8 * 8);
        float4 a = q[0], b = q[1];
        *(bf16x8*)((char*)Wl + n * 1024 + ((k8 * 16) ^ ((n & 7) << 4))) = pack8(a, b);
    }
    // norm + store X tile 0 (scale folded into stored bf16)
    auto putX = [&](int m, float4 a, float4 b) {
        float ss = a.x*a.x + a.y*a.y + a.z*a.z + a.w*a.w
                 + b.x*b.x + b.y*b.y + b.z*b.z + b.w*b.w;
        #pragma unroll
        for (int d = 1; d < 64; d <<= 1) ss += __shfl_xor(ss, d);
        float scl = (ss > 0.f) ? (1.f / sqrtf(ss)) : 0.f;
        *(bf16x8*)((char*)Xl + m * 1024 + ((lane * 16) ^ ((m & 7) << 4))) = pack8s(a, b, scl);
    };
    putX(w,     ga0, ga1);
    putX(w + 8, gb0, gb1);
    __syncthreads();

    for (int it = 0; it < 5; ++it) {
        // prefetch next tile's gather volley (hides HBM latency under MFMA)
        float4 na0, na1, nb0, nb1;
        if (it < 4) {
            int tile = tile0 + it + 1;
            int r0 = idx[tile * 16 + w];
            int r1 = idx[tile * 16 + w + 8];
            const float4* p0 = (const float4*)(XS + (size_t)r0 * NFEAT + lane * 8);
            const float4* p1 = (const float4*)(XS + (size_t)r1 * NFEAT + lane * 8);
            na0 = p0[0]; na1 = p0[1];
            nb0 = p1[0]; nb1 = p1[1];
        }
        // compute: wave w -> output cols w*16..w*16+15; both operands from LDS
        f32x4 accE = zero4, accO = zero4;
        #pragma unroll
        for (int kc = 0; kc < 16; ++kc) {
            bf16x8 a = ldsAx(Xl, ln,          kc * 64 + lg * 16, 1024);
            bf16x8 b = ldsAx(Wl, w * 16 + ln, kc * 64 + lg * 16, 1024);
            if (kc & 1) accO = MFMA(a, b, accO); else accE = MFMA(a, b, accE);
        }
        f32x4 acc = accE + accO;
        #pragma unroll
        for (int rg = 0; rg < 4; ++rg)
            ldsW1(Hl, lg * 4 + rg, w * 16 + ln, f2bf(fmaxf(acc[rg], 0.f)));
        __syncthreads();   // X reads + Hl writes complete

        // H tile -> ws (coalesced 4 KB), overlapped with next-X store
        if (tid < 256) {
            int tile = tile0 + it;
            ((uint4*)(wsH + ((size_t)t * NIDX + (size_t)tile * 16) * NHID))[tid]
                = ((const uint4*)Hl)[tid];
        }
        if (it < 4) {
            putX(w,     na0, na1);
            putX(w + 8, nb0, nb1);
        }
        __syncthreads();   // Xl ready, Hl copy drained
    }
}

// ---- kernel 2: tail C/D/E + softmax; weight fragments volleyed from f32 in L2 ----
__global__ __launch_bounds__(512) void tailCDE(
    const float* __restrict__ G1, const float* __restrict__ G2,
    const float* __restrict__ GT, const float* __restrict__ Wc,
    const unsigned short* __restrict__ wsH,
    float* __restrict__ out)
{
    __shared__ __align__(16) unsigned short Hbuf[2][16][NHID]; // 8 KB (swizzle baked)
    __shared__ __align__(16) unsigned short Scr[8704];         // G12 | FIX | LOG
    __shared__ float scl2[16];

    unsigned short* G12 = Scr;
    unsigned short* FIX = Scr + 4096;
    float*          LOG = (float*)(Scr + 6144);

    const int tid  = threadIdx.x;
    const int bid  = blockIdx.x;
    const int w    = tid >> 6;
    const int lane = tid & 63;
    const int ln   = lane & 15, lg = lane >> 4;
    const int tB = w >> 2, nq = w & 3;
    const f32x4 zero4 = {0.f, 0.f, 0.f, 0.f};

    // --- entry volley 1: H tiles + stage-C fragments (f32) ---
    uint4 hv;
    {
        int tt = tid >> 8, r = tid & 255;
        hv = *(const uint4*)((const char*)wsH
                + ((size_t)tt * NIDX + (size_t)bid * 16) * 256 + r * 16);
    }
    bf16x8 cf[8];
    {
        const float* Gp = tB ? G2 : G1;
        float4 ca[8], cb[8];
        #pragma unroll
        for (int kc = 0; kc < 4; ++kc)
            #pragma unroll
            for (int nt = 0; nt < 2; ++nt) {
                const float4* p = (const float4*)(Gp + (size_t)(nq * 32 + nt * 16 + ln) * NHID + kc * 32 + lg * 8);
                ca[kc * 2 + nt] = p[0]; cb[kc * 2 + nt] = p[1];
            }
        ((uint4*)&Hbuf[0][0][0])[tid] = hv;
        #pragma unroll
        for (int i = 0; i < 8; ++i) cf[i] = pack8(ca[i], cb[i]);
    }
    // --- volley 2: stage-D fragments (complete under stage C) ---
    const int nD = w * 16 + ln;
    float4 da[8], db[8];
    {
        const float* gp = GT + (size_t)nD * (2 * NHID) + lg * 8;
        #pragma unroll
        for (int kc = 0; kc < 8; ++kc) {
            const float4* p = (const float4*)(gp + kc * 32);
            da[kc] = p[0]; db[kc] = p[1];
        }
    }
    __syncthreads();

    // stage C: gate1/gate2 = H[t] @ G{1,2}^T
    {
        const unsigned short* Hs = &Hbuf[tB][0][0];
        f32x4 accC[2] = {zero4, zero4};
        #pragma unroll
        for (int kc = 0; kc < 4; ++kc) {
            bf16x8 a = ldsAx(Hs, ln, kc * 64 + lg * 16, 256);
            accC[0] = MFMA(a, cf[kc * 2],     accC[0]);
            accC[1] = MFMA(a, cf[kc * 2 + 1], accC[1]);
        }
        unsigned short* Gd = G12 + tB * 2048;
        #pragma unroll
        for (int nt = 0; nt < 2; ++nt)
            #pragma unroll
            for (int rg = 0; rg < 4; ++rg) {
                int m = lg * 4 + rg;
                ldsW1(Gd, m, nq * 32 + nt * 16 + ln, f2bf(accC[nt][rg]));
            }
    }
    // pack stage-D fragments; volley 3: stage-E fragments (complete under stage D)
    bf16x8 gt[8];
    #pragma unroll
    for (int i = 0; i < 8; ++i) gt[i] = pack8(da[i], db[i]);
    const int ccE = w * 16 + ln;
    const int ccl = (ccE < NCLASS) ? ccE : 0;
    float4 ea[4], eb[4];
    {
        const float* wp = Wc + (size_t)ccl * NHID + lg * 8;
        #pragma unroll
        for (int kc = 0; kc < 4; ++kc) {
            const float4* p = (const float4*)(wp + kc * 32);
            ea[kc] = p[0]; eb[kc] = p[1];
        }
    }
    __syncthreads();

    // stage D: gate = sigmoid([g1,g2] @ GT^T); fix = (1-g)H0 + gH1
    {
        f32x4 accE_ = zero4, accO_ = zero4;
        #pragma unroll
        for (int kc = 0; kc < 8; ++kc) {
            const unsigned short* As = G12 + (kc >> 2) * 2048;
            bf16x8 a = ldsAx(As, ln, (kc & 3) * 64 + lg * 16, 256);
            if (kc & 1) accO_ = MFMA(a, gt[kc], accO_); else accE_ = MFMA(a, gt[kc], accE_);
        }
        f32x4 accD = accE_ + accO_;
        #pragma unroll
        for (int rg = 0; rg < 4; ++rg) {
            int m = lg * 4 + rg;
            float g  = 1.f / (1.f + __expf(-accD[rg]));
            float h0 = ldsR1(&Hbuf[0][0][0], m, nD);
            float h1 = ldsR1(&Hbuf[1][0][0], m, nD);
            ldsW1(FIX, m, nD, f2bf((1.f - g) * h0 + g * h1));
        }
    }
    __syncthreads();

    // fix_inner row norms -> scl2
    if (tid < 256) {
        int r = tid >> 4, sl = tid & 15;
        bf16x8 v = ldsAx(FIX, r, sl * 16, 256);
        float ss = 0.f;
        #pragma unroll
        for (int j = 0; j < 8; ++j) { float f = (float)v[j]; ss += f * f; }
        ss += __shfl_xor(ss, 1); ss += __shfl_xor(ss, 2);
        ss += __shfl_xor(ss, 4); ss += __shfl_xor(ss, 8);
        if (sl == 0) scl2[r] = (ss > 0.f) ? (1.f / sqrtf(ss)) : 0.f;
    }
    __syncthreads();

    // stage E: logits = relu(scl2 * fix @ Wc^T)
    if (w < 5) {
        const bool live = (ccE < NCLASS);
        bf16x8 bfz;
        #pragma unroll
        for (int j = 0; j < 8; ++j) bfz[j] = (__bf16)0.f;
        f32x4 accE = zero4;
        #pragma unroll
        for (int kc = 0; kc < 4; ++kc) {
            bf16x8 a = ldsAx(FIX, ln, kc * 64 + lg * 16, 256);
            bf16x8 b = live ? pack8(ea[kc], eb[kc]) : bfz;
            accE = MFMA(a, b, accE);
        }
        #pragma unroll
        for (int rg = 0; rg < 4; ++rg) {
            int m = lg * 4 + rg;
            float v = fmaxf(accE[rg] * scl2[m], 0.f);
            LOG[m * 80 + ccE] = live ? v : -1e30f;
        }
    }
    __syncthreads();

    // log_softmax + store
    {
        const int r = tid >> 5, l32 = tid & 31;
        float v0 = LOG[r * 80 + l32];
        float v1 = LOG[r * 80 + 32 + l32];
        float v2 = (l32 < 16) ? LOG[r * 80 + 64 + l32] : -1e30f;
        float mx = fmaxf(fmaxf(v0, v1), v2);
        #pragma unroll
        for (int d = 1; d < 32; d <<= 1) mx = fmaxf(mx, __shfl_xor(mx, d, 32));
        float se = __expf(v0 - mx) + __expf(v1 - mx) + ((l32 < 16) ? __expf(v2 - mx) : 0.f);
        #pragma unroll
        for (int d = 1; d < 32; d <<= 1) se += __shfl_xor(se, d, 32);
        float lz = mx + __logf(se);
        size_t orow = (size_t)bid * 16 + r;
        out[orow * NCLASS + l32] = v0 - lz;
        if (l32 + 32 < NCLASS) out[orow * NCLASS + 32 + l32] = v1 - lz;
        if (l32 + 64 < NCLASS) out[orow * NCLASS + 64 + l32] = v2 - lz;
    }
}

// ---- fallback (ws too small): fused kernel, f32 weights inline ----
static __device__ __forceinline__ bf16x8 bfragF(const float* p, size_t off) {
    const float4* q = (const float4*)(p + off);
    return pack8(q[0], q[1]);
}
__global__ __launch_bounds__(512) void hyper_fb(
    const float* __restrict__ x, const float* __restrict__ sf,
    const int* __restrict__ idx,
    const float* __restrict__ W0, const float* __restrict__ W1,
    const float* __restrict__ G1, const float* __restrict__ G2,
    const float* __restrict__ GT, const float* __restrict__ Wc,
    float* __restrict__ out)
{
    __shared__ __align__(16) unsigned short Xbuf[2][16][NFEAT];
    __shared__ __align__(16) unsigned short Hbuf[2][16][NHID];
    __shared__ float scl2[16];
    unsigned short* G12 = &Xbuf[0][0][0];
    unsigned short* FIX = &Xbuf[0][0][0] + 4096;
    float*          LOG = (float*)(&Xbuf[0][0][0] + 6144);

    const int tid = threadIdx.x, bid = blockIdx.x;
    const int w = tid >> 6, lane = tid & 63;
    const int ln = lane & 15, lg = lane >> 4;
    const int tB = w >> 2, nq = w & 3;
    const f32x4 zero4 = {0.f, 0.f, 0.f, 0.f};

    {
        char* xb = (char*)&Xbuf[0][0][0];
        #pragma unroll
        for (int j = 0; j < 4; ++j) {
            int p = w * 4 + j, t = p >> 4, m = p & 15;
            int ri = idx[bid * 16 + m];
            const float4* q = (const float4*)((t ? sf : x) + (size_t)ri * NFEAT + lane * 8);
            float4 a = q[0], b = q[1];
            float ss = a.x*a.x + a.y*a.y + a.z*a.z + a.w*a.w
                     + b.x*b.x + b.y*b.y + b.z*b.z + b.w*b.w;
            #pragma unroll
            for (int d = 1; d < 64; d <<= 1) ss += __shfl_xor(ss, d);
            float scl = (ss > 0.f) ? (1.f / sqrtf(ss)) : 0.f;
            int soff = t * 16384 + m * 1024 + ((lane * 16) ^ ((m & 7) << 4));
            *(bf16x8*)(xb + soff) = pack8s(a, b, scl);
        }
    }
    __syncthreads();
    {
        const float* Wp = tB ? W1 : W0;
        f32x4 acc0 = zero4, acc1 = zero4;
        const unsigned short* Xb = (const unsigned short*)((const char*)&Xbuf[0][0][0] + tB * 16384);
        #pragma unroll
        for (int kc = 0; kc < 16; ++kc) {
            bf16x8 a = ldsAx(Xb, ln, kc * 64 + lg * 16, 1024);
            acc0 = MFMA(a, bfragF(Wp, (size_t)(nq * 32 + ln) * NFEAT + kc * 32 + lg * 8), acc0);
            acc1 = MFMA(a, bfragF(Wp, (size_t)(nq * 32 + 16 + ln) * NFEAT + kc * 32 + lg * 8), acc1);
        }
        unsigned short* Hb = &Hbuf[tB][0][0];
        #pragma unroll
        for (int rg = 0; rg < 4; ++rg) {
            int m = lg * 4 + rg;
            ldsW1(Hb, m, nq * 32 + ln,      f2bf(fmaxf(acc0[rg], 0.f)));
            ldsW1(Hb, m, nq * 32 + 16 + ln, f2bf(fmaxf(acc1[rg], 0.f)));
        }
    }
    __syncthreads();
    {
        const float* Gp = tB ? G2 : G1;
        const unsigned short* Hs = &Hbuf[tB][0][0];
        f32x4 accC[2] = {zero4, zero4};
        #pragma unroll
        for (int kc = 0; kc < 4; ++kc) {
            bf16x8 a = ldsAx(Hs, ln, kc * 64 + lg * 16, 256);
            accC[0] = MFMA(a, bfragF(Gp, (size_t)(nq * 32 + ln) * NHID + kc * 32 + lg * 8), accC[0]);
            accC[1] = MFMA(a, bfragF(Gp, (size_t)(nq * 32 + 16 + ln) * NHID + kc * 32 + lg * 8), accC[1]);
        }
        unsigned short* Gd = G12 + tB * 2048;
        #pragma unroll
        for (int nt = 0; nt < 2; ++nt)
            #pragma unroll
            for (int rg = 0; rg < 4; ++rg) {
                int m = lg * 4 + rg;
                ldsW1(Gd, m, nq * 32 + nt * 16 + ln, f2bf(accC[nt][rg]));
            }
    }
    __syncthreads();
    {
        f32x4 accD = zero4;
        const int n = w * 16 + ln;
        #pragma unroll
        for (int kc = 0; kc < 8; ++kc) {
            const unsigned short* As = G12 + (kc >> 2) * 2048;
            bf16x8 a = ldsAx(As, ln, (kc & 3) * 64 + lg * 16, 256);
            accD = MFMA(a, bfragF(GT, (size_t)n * (2 * NHID) + kc * 32 + lg * 8), accD);
        }
        #pragma unroll
        for (int rg = 0; rg < 4; ++rg) {
            int m = lg * 4 + rg;
            float g  = 1.f / (1.f + __expf(-accD[rg]));
            float h0 = ldsR1(&Hbuf[0][0][0], m, n);
            float h1 = ldsR1(&Hbuf[1][0][0], m, n);
            ldsW1(FIX, m, n, f2bf((1.f - g) * h0 + g * h1));
        }
    }
    __syncthreads();
    if (tid < 256) {
        int r = tid >> 4, sl = tid & 15;
        bf16x8 v = ldsAx(FIX, r, sl * 16, 256);
        float ss = 0.f;
        #pragma unroll
        for (int j = 0; j < 8; ++j) { float f = (float)v[j]; ss += f * f; }
        ss += __shfl_xor(ss, 1); ss += __shfl_xor(ss, 2);
        ss += __shfl_xor(ss, 4); ss += __shfl_xor(ss, 8);
        if (sl == 0) scl2[r] = (ss > 0.f) ? (1.f / sqrtf(ss)) : 0.f;
    }
    __syncthreads();
    if (w < 5) {
        const int cc = w * 16 + ln;
        bf16x8 bfz;
        #pragma unroll
        for (int j = 0; j < 8; ++j) bfz[j] = (__bf16)0.f;
        f32x4 accE = zero4;
        #pragma unroll
        for (int kc = 0; kc < 4; ++kc) {
            bf16x8 a = ldsAx(FIX, ln, kc * 64 + lg * 16, 256);
            bf16x8 b = (cc < NCLASS) ? bfragF(Wc, (size_t)cc * NHID + kc * 32 + lg * 8) : bfz;
            accE = MFMA(a, b, accE);
        }
        #pragma unroll
        for (int rg = 0; rg < 4; ++rg) {
            int m = lg * 4 + rg;
            float v = fmaxf(accE[rg] * scl2[m], 0.f);
            LOG[m * 80 + cc] = (cc < NCLASS) ? v : -1e30f;
        }
    }
    __syncthreads();
    {
        const int r = tid >> 5, l32 = tid & 31;
        float v0 = LOG[r * 80 + l32];
        float v1 = LOG[r * 80 + 32 + l32];
        float v2 = (l32 < 16) ? LOG[r * 80 + 64 + l32] : -1e30f;
        float mx = fmaxf(fmaxf(v0, v1), v2);
        #pragma unroll
        for (int d = 1; d < 32; d <<= 1) mx = fmaxf(mx, __shfl_xor(mx, d, 32));
        float se = __expf(v0 - mx) + __expf(v1 - mx) + ((l32 < 16) ? __expf(v2 - mx) : 0.f);
        #pragma unroll
        for (int d = 1; d < 32; d <<= 1) se += __shfl_xor(se, d, 32);
        float lz = mx + __logf(se);
        size_t orow = (size_t)bid * 16 + r;
        out[orow * NCLASS + l32] = v0 - lz;
        if (l32 + 32 < NCLASS) out[orow * NCLASS + 32 + l32] = v1 - lz;
        if (l32 + 64 < NCLASS) out[orow * NCLASS + 64 + l32] = v2 - lz;
    }
}

extern "C" void kernel_launch(void* const* d_in, const int* in_sizes, int n_in,
                              void* d_out, int out_size, void* d_ws, size_t ws_size,
                              hipStream_t stream)
{
    const float* x   = (const float*)d_in[0];
    const float* sf  = (const float*)d_in[1];
    const int*   idx = (const int*)d_in[2];
    const float* W0  = (const float*)d_in[3];
    const float* W1  = (const float*)d_in[4];
    const float* G1  = (const float*)d_in[5];
    const float* G2  = (const float*)d_in[6];
    const float* GT  = (const float*)d_in[7];
    const float* Wc  = (const float*)d_in[8];
    float* out = (float*)d_out;

    if (ws_size >= WS_NEED) {
        unsigned short* wsH = (unsigned short*)d_ws;
        stageB_ws<<<dim3(250), dim3(512), 0, stream>>>(x, sf, idx, W0, W1, wsH);
        tailCDE<<<dim3(NTILE), dim3(512), 0, stream>>>(G1, G2, GT, Wc, wsH, out);
    } else {
        hyper_fb<<<dim3(NTILE), dim3(512), 0, stream>>>(
            x, sf, idx, W0, W1, G1, G2, GT, Wc, out);
    }
}

// Round 11
// 37.167 us; speedup vs baseline: 1.3736x; 1.3736x over previous
//
#include <hip/hip_runtime.h>
#include <math.h>

#define NFEAT  512
#define NHID   128
#define NCLASS 70
#define NIDX   10000
#define NTILE  625
#define NT2    313                         // tail blocks: 2 tiles each (last has 1)
#define HELEMS (2u * NIDX * NHID)          // 2,560,000 ushorts: H scratch
#define WIMG_ELEMS (2u * 128 * 512)        // 131,072 ushorts: W0/W1 LDS images
#define SMALL_ELEMS 74496u                 // G1,G2,GT,Wc row-major bf16
#define WS_NEED ((size_t)(HELEMS + WIMG_ELEMS + SMALL_ELEMS) * 2)

typedef float  f32x4  __attribute__((ext_vector_type(4)));
typedef __bf16 bf16x8 __attribute__((ext_vector_type(8)));

static __device__ __forceinline__ unsigned short f2bf(float f) {
    unsigned u = __builtin_bit_cast(unsigned, f);
    u += 0x7fffu + ((u >> 16) & 1u);
    return (unsigned short)(u >> 16);
}
static __device__ __forceinline__ float bf2f(unsigned short h) {
    unsigned u = ((unsigned)h) << 16;
    return __builtin_bit_cast(float, u);
}
static __device__ __forceinline__ bf16x8 pack8(float4 a, float4 b) {
    bf16x8 r;
    r[0] = (__bf16)a.x; r[1] = (__bf16)a.y; r[2] = (__bf16)a.z; r[3] = (__bf16)a.w;
    r[4] = (__bf16)b.x; r[5] = (__bf16)b.y; r[6] = (__bf16)b.z; r[7] = (__bf16)b.w;
    return r;
}
static __device__ __forceinline__ bf16x8 pack8s(float4 a, float4 b, float s) {
    bf16x8 r;
    r[0] = (__bf16)(a.x * s); r[1] = (__bf16)(a.y * s); r[2] = (__bf16)(a.z * s); r[3] = (__bf16)(a.w * s);
    r[4] = (__bf16)(b.x * s); r[5] = (__bf16)(b.y * s); r[6] = (__bf16)(b.z * s); r[7] = (__bf16)(b.w * s);
    return r;
}
static __device__ __forceinline__ f32x4 MFMA(bf16x8 a, bf16x8 b, f32x4 c) {
    return __builtin_amdgcn_mfma_f32_16x16x32_bf16(a, b, c, 0, 0, 0);
}
static __device__ __forceinline__ bf16x8 ldsAx(const unsigned short* base, int row, int colb, int rstride) {
    return *(const bf16x8*)((const char*)base + row * rstride + (colb ^ ((row & 7) << 4)));
}
static __device__ __forceinline__ void ldsW1(unsigned short* base, int row, int col, unsigned short v) {
    *(unsigned short*)((char*)base + row * 256 + ((col * 2) ^ ((row & 7) << 4))) = v;
}
static __device__ __forceinline__ float ldsR1(const unsigned short* base, int row, int col) {
    return bf2f(*(const unsigned short*)((const char*)base + row * 256 + ((col * 2) ^ ((row & 7) << 4))));
}

// ---- prep: W0/W1 -> pre-swizzled bf16 LDS images; G1/G2/GT/Wc -> row-major bf16 ----
__global__ void prep_weights(const float* __restrict__ W0, const float* __restrict__ W1,
                             const float* __restrict__ G1, const float* __restrict__ G2,
                             const float* __restrict__ GT, const float* __restrict__ Wc,
                             unsigned short* __restrict__ wsWimg,
                             unsigned short* __restrict__ wsSmall) {
    int i = blockIdx.x * 256 + threadIdx.x;
    if (i < 16384) {
        int t = i >> 13;
        int r = i & 8191;
        int n = r >> 6, k8 = r & 63;
        const float* src = (t ? W1 : W0) + (size_t)n * NFEAT + k8 * 8;
        float4 a = ((const float4*)src)[0], b = ((const float4*)src)[1];
        char* dst = (char*)wsWimg + t * 131072 + n * 1024 + ((k8 * 16) ^ ((n & 7) << 4));
        *(bf16x8*)dst = pack8(a, b);
    } else {
        int i4 = i - 16384;
        if (i4 >= 18624) return;
        const float* src; int base4, dstb;
        if      (i4 < 4096)  { src = G1; base4 = 0;     dstb = 0; }
        else if (i4 < 8192)  { src = G2; base4 = 4096;  dstb = 16384; }
        else if (i4 < 16384) { src = GT; base4 = 8192;  dstb = 32768; }
        else                 { src = Wc; base4 = 16384; dstb = 65536; }
        float4 v = ((const float4*)src)[i4 - base4];
        ushort4 o;
        o.x = f2bf(v.x); o.y = f2bf(v.y); o.z = f2bf(v.z); o.w = f2bf(v.w);
        *(ushort4*)(wsSmall + dstb + (size_t)(i4 - base4) * 4) = o;
    }
}

// ---- stage B, weights-stationary (r9, proven): 250 blocks, 5 tiles each ----
__global__ __launch_bounds__(512) void stageB_ws(
    const float* __restrict__ x, const float* __restrict__ sf,
    const int* __restrict__ idx,
    const unsigned short* __restrict__ wsWimg,
    unsigned short* __restrict__ wsH)
{
    __shared__ __align__(16) unsigned short Wl[65536];  // 128 KB swizzled W image
    __shared__ __align__(16) unsigned short Xl[8192];   // 16 KB swizzled X tile
    __shared__ __align__(16) unsigned short Hl[2048];   // 4 KB swizzled H tile

    const int tid  = threadIdx.x;
    const int w    = tid >> 6;
    const int lane = tid & 63;
    const int ln   = lane & 15, lg = lane >> 4;
    const int bid  = blockIdx.x;
    const int t    = bid / 125, tb = bid % 125;
    const int tile0 = tb * 5;
    const float* XS = t ? sf : x;
    const f32x4 zero4 = {0.f, 0.f, 0.f, 0.f};

    float4 ga0, ga1, gb0, gb1;
    {
        int r0 = idx[tile0 * 16 + w];
        int r1 = idx[tile0 * 16 + w + 8];
        const float4* p0 = (const float4*)(XS + (size_t)r0 * NFEAT + lane * 8);
        const float4* p1 = (const float4*)(XS + (size_t)r1 * NFEAT + lane * 8);
        ga0 = p0[0]; ga1 = p0[1];
        gb0 = p1[0]; gb1 = p1[1];
    }
    {
        const uint4* src = (const uint4*)((const char*)wsWimg + (size_t)t * 131072);
        uint4* dst = (uint4*)Wl;
        #pragma unroll
        for (int i = 0; i < 16; ++i) dst[tid + i * 512] = src[tid + i * 512];
    }
    auto putX = [&](int m, float4 a, float4 b) {
        float ss = a.x*a.x + a.y*a.y + a.z*a.z + a.w*a.w
                 + b.x*b.x + b.y*b.y + b.z*b.z + b.w*b.w;
        #pragma unroll
        for (int d = 1; d < 64; d <<= 1) ss += __shfl_xor(ss, d);
        float scl = (ss > 0.f) ? (1.f / sqrtf(ss)) : 0.f;
        *(bf16x8*)((char*)Xl + m * 1024 + ((lane * 16) ^ ((m & 7) << 4))) = pack8s(a, b, scl);
    };
    putX(w,     ga0, ga1);
    putX(w + 8, gb0, gb1);
    __syncthreads();

    for (int it = 0; it < 5; ++it) {
        float4 na0, na1, nb0, nb1;
        if (it < 4) {
            int tile = tile0 + it + 1;
            int r0 = idx[tile * 16 + w];
            int r1 = idx[tile * 16 + w + 8];
            const float4* p0 = (const float4*)(XS + (size_t)r0 * NFEAT + lane * 8);
            const float4* p1 = (const float4*)(XS + (size_t)r1 * NFEAT + lane * 8);
            na0 = p0[0]; na1 = p0[1];
            nb0 = p1[0]; nb1 = p1[1];
        }
        f32x4 accE = zero4, accO = zero4;
        #pragma unroll
        for (int kc = 0; kc < 16; ++kc) {
            bf16x8 a = ldsAx(Xl, ln,          kc * 64 + lg * 16, 1024);
            bf16x8 b = ldsAx(Wl, w * 16 + ln, kc * 64 + lg * 16, 1024);
            if (kc & 1) accO = MFMA(a, b, accO); else accE = MFMA(a, b, accE);
        }
        f32x4 acc = accE + accO;
        #pragma unroll
        for (int rg = 0; rg < 4; ++rg)
            ldsW1(Hl, lg * 4 + rg, w * 16 + ln, f2bf(fmaxf(acc[rg], 0.f)));
        __syncthreads();

        if (tid < 256) {
            int tile = tile0 + it;
            ((uint4*)(wsH + ((size_t)t * NIDX + (size_t)tile * 16) * NHID))[tid]
                = ((const uint4*)Hl)[tid];
        }
        if (it < 4) {
            putX(w,     na0, na1);
            putX(w + 8, nb0, nb1);
        }
        __syncthreads();
    }
}

// ---- tail: 2 tiles per block; fragment volleys amortized across tiles ----
__global__ __launch_bounds__(512) void tailCDE2(
    const unsigned short* __restrict__ wsSmall,
    const unsigned short* __restrict__ wsH,
    float* __restrict__ out)
{
    __shared__ __align__(16) unsigned short Hbuf[2][2][16][NHID]; // 16 KB (tile, tensor)
    __shared__ __align__(16) unsigned short G12s[2][2][16][NHID]; // 16 KB; LOG aliases
    __shared__ __align__(16) unsigned short FIXs[2][16][NHID];    // 8 KB
    __shared__ float scl2[2][16];

    const unsigned short* G1p = wsSmall;
    const unsigned short* G2p = wsSmall + 16384;
    const unsigned short* GTp = wsSmall + 32768;
    const unsigned short* Wcp = wsSmall + 65536;

    const int tid  = threadIdx.x;
    const int bid  = blockIdx.x;
    const int w    = tid >> 6;
    const int lane = tid & 63;
    const int ln   = lane & 15, lg = lane >> 4;
    const int tB = w >> 2, nq = w & 3;
    const f32x4 zero4 = {0.f, 0.f, 0.f, 0.f};
    const int tile0 = bid * 2;
    const int tileC1 = (tile0 + 1 < NTILE) ? tile0 + 1 : NTILE - 1;  // clamped

    // --- entry volleys: H tiles (both), cf, gt — all independent ---
    {
        int tt = tid >> 8, r = tid & 255;
        uint4 v0 = *(const uint4*)((const char*)wsH
                + ((size_t)tt * NIDX + (size_t)tile0 * 16) * 256 + r * 16);
        uint4 v1 = *(const uint4*)((const char*)wsH
                + ((size_t)tt * NIDX + (size_t)tileC1 * 16) * 256 + r * 16);
        ((uint4*)&Hbuf[0][0][0][0])[tid] = v0;
        ((uint4*)&Hbuf[1][0][0][0])[tid] = v1;
    }
    bf16x8 cf[8];
    {
        const unsigned short* Gp = tB ? G2p : G1p;
        #pragma unroll
        for (int kc = 0; kc < 4; ++kc)
            #pragma unroll
            for (int nt = 0; nt < 2; ++nt)
                cf[kc * 2 + nt] = *(const bf16x8*)(Gp + (size_t)(nq * 32 + nt * 16 + ln) * NHID + kc * 32 + lg * 8);
    }
    const int nD = w * 16 + ln;
    bf16x8 gt[8];
    #pragma unroll
    for (int kc = 0; kc < 8; ++kc)
        gt[kc] = *(const bf16x8*)(GTp + (size_t)nD * (2 * NHID) + kc * 32 + lg * 8);
    __syncthreads();   // b1

    // --- stage C: both tiles ---
    #pragma unroll
    for (int ti = 0; ti < 2; ++ti) {
        const unsigned short* Hs = &Hbuf[ti][tB][0][0];
        f32x4 accC[2] = {zero4, zero4};
        #pragma unroll
        for (int kc = 0; kc < 4; ++kc) {
            bf16x8 a = ldsAx(Hs, ln, kc * 64 + lg * 16, 256);
            accC[0] = MFMA(a, cf[kc * 2],     accC[0]);
            accC[1] = MFMA(a, cf[kc * 2 + 1], accC[1]);
        }
        unsigned short* Gd = &G12s[ti][tB][0][0];
        #pragma unroll
        for (int nt = 0; nt < 2; ++nt)
            #pragma unroll
            for (int rg = 0; rg < 4; ++rg) {
                int m = lg * 4 + rg;
                ldsW1(Gd, m, nq * 32 + nt * 16 + ln, f2bf(accC[nt][rg]));
            }
    }
    // stage-E fragments (bf16, clamped row): complete under stage D
    const int ccE = w * 16 + ln;
    const int ccl = (ccE < NCLASS) ? ccE : 0;
    bf16x8 wcf[4];
    #pragma unroll
    for (int kc = 0; kc < 4; ++kc)
        wcf[kc] = *(const bf16x8*)(Wcp + (size_t)ccl * NHID + kc * 32 + lg * 8);
    __syncthreads();   // b2

    // --- stage D: both tiles ---
    #pragma unroll
    for (int ti = 0; ti < 2; ++ti) {
        f32x4 aE = zero4, aO = zero4;
        #pragma unroll
        for (int kc = 0; kc < 8; ++kc) {
            const unsigned short* As = &G12s[ti][kc >> 2][0][0];
            bf16x8 a = ldsAx(As, ln, (kc & 3) * 64 + lg * 16, 256);
            if (kc & 1) aO = MFMA(a, gt[kc], aO); else aE = MFMA(a, gt[kc], aE);
        }
        f32x4 accD = aE + aO;
        #pragma unroll
        for (int rg = 0; rg < 4; ++rg) {
            int m = lg * 4 + rg;
            float g  = 1.f / (1.f + __expf(-accD[rg]));
            float h0 = ldsR1(&Hbuf[ti][0][0][0], m, nD);
            float h1 = ldsR1(&Hbuf[ti][1][0][0], m, nD);
            ldsW1(&FIXs[ti][0][0], m, nD, f2bf((1.f - g) * h0 + g * h1));
        }
    }
    __syncthreads();   // b3

    // --- fix norms: 512 threads = 32 rows x 16 lanes ---
    {
        int rr = tid >> 4, sl = tid & 15;
        int ti = rr >> 4, r = rr & 15;
        bf16x8 v = ldsAx(&FIXs[ti][0][0], r, sl * 16, 256);
        float ss = 0.f;
        #pragma unroll
        for (int j = 0; j < 8; ++j) { float f = (float)v[j]; ss += f * f; }
        ss += __shfl_xor(ss, 1); ss += __shfl_xor(ss, 2);
        ss += __shfl_xor(ss, 4); ss += __shfl_xor(ss, 8);
        if (sl == 0) scl2[ti][r] = (ss > 0.f) ? (1.f / sqrtf(ss)) : 0.f;
    }
    __syncthreads();   // b4

    // --- stage E: both tiles (waves 0..4); LOG aliases G12s (dead) ---
    if (w < 5) {
        const bool live = (ccE < NCLASS);
        bf16x8 bfz;
        #pragma unroll
        for (int j = 0; j < 8; ++j) bfz[j] = (__bf16)0.f;
        #pragma unroll
        for (int ti = 0; ti < 2; ++ti) {
            f32x4 accE = zero4;
            #pragma unroll
            for (int kc = 0; kc < 4; ++kc) {
                bf16x8 a = ldsAx(&FIXs[ti][0][0], ln, kc * 64 + lg * 16, 256);
                accE = MFMA(a, live ? wcf[kc] : bfz, accE);
            }
            if (live) {
                float* LO = (float*)((char*)&G12s[0][0][0][0] + ti * 8192);
                #pragma unroll
                for (int rg = 0; rg < 4; ++rg) {
                    int m = lg * 4 + rg;
                    LO[m * 80 + ccE] = fmaxf(accE[rg] * scl2[ti][m], 0.f);
                }
            }
        }
    }
    __syncthreads();   // b5

    // --- log_softmax + store: 32 rows x 16 lanes, 5 classes per lane ---
    {
        int rr = tid >> 4, l16 = tid & 15;
        int ti = rr >> 4, r = rr & 15;
        const float* LO = (const float*)((const char*)&G12s[0][0][0][0] + ti * 8192) + r * 80;
        float v[5];
        #pragma unroll
        for (int j = 0; j < 5; ++j) {
            int c = l16 + j * 16;
            v[j] = (c < NCLASS) ? LO[c] : -1e30f;
        }
        float mx = v[0];
        #pragma unroll
        for (int j = 1; j < 5; ++j) mx = fmaxf(mx, v[j]);
        mx = fmaxf(mx, __shfl_xor(mx, 1)); mx = fmaxf(mx, __shfl_xor(mx, 2));
        mx = fmaxf(mx, __shfl_xor(mx, 4)); mx = fmaxf(mx, __shfl_xor(mx, 8));
        float se = 0.f;
        #pragma unroll
        for (int j = 0; j < 5; ++j) {
            int c = l16 + j * 16;
            if (c < NCLASS) se += __expf(v[j] - mx);
        }
        se += __shfl_xor(se, 1); se += __shfl_xor(se, 2);
        se += __shfl_xor(se, 4); se += __shfl_xor(se, 8);
        float lz = mx + __logf(se);
        int tile = tile0 + ti;
        if (tile < NTILE) {
            size_t orow = (size_t)tile * 16 + r;
            #pragma unroll
            for (int j = 0; j < 5; ++j) {
                int c = l16 + j * 16;
                if (c < NCLASS) out[orow * NCLASS + c] = v[j] - lz;
            }
        }
    }
}

// ---- fallback (ws too small): fused kernel, f32 weights inline ----
static __device__ __forceinline__ bf16x8 bfragF(const float* p, size_t off) {
    const float4* q = (const float4*)(p + off);
    return pack8(q[0], q[1]);
}
__global__ __launch_bounds__(512) void hyper_fb(
    const float* __restrict__ x, const float* __restrict__ sf,
    const int* __restrict__ idx,
    const float* __restrict__ W0, const float* __restrict__ W1,
    const float* __restrict__ G1, const float* __restrict__ G2,
    const float* __restrict__ GT, const float* __restrict__ Wc,
    float* __restrict__ out)
{
    __shared__ __align__(16) unsigned short Xbuf[2][16][NFEAT];
    __shared__ __align__(16) unsigned short Hbuf[2][16][NHID];
    __shared__ float scl2[16];
    unsigned short* G12 = &Xbuf[0][0][0];
    unsigned short* FIX = &Xbuf[0][0][0] + 4096;
    float*          LOG = (float*)(&Xbuf[0][0][0] + 6144);

    const int tid = threadIdx.x, bid = blockIdx.x;
    const int w = tid >> 6, lane = tid & 63;
    const int ln = lane & 15, lg = lane >> 4;
    const int tB = w >> 2, nq = w & 3;
    const f32x4 zero4 = {0.f, 0.f, 0.f, 0.f};

    {
        char* xb = (char*)&Xbuf[0][0][0];
        #pragma unroll
        for (int j = 0; j < 4; ++j) {
            int p = w * 4 + j, t = p >> 4, m = p & 15;
            int ri = idx[bid * 16 + m];
            const float4* q = (const float4*)((t ? sf : x) + (size_t)ri * NFEAT + lane * 8);
            float4 a = q[0], b = q[1];
            float ss = a.x*a.x + a.y*a.y + a.z*a.z + a.w*a.w
                     + b.x*b.x + b.y*b.y + b.z*b.z + b.w*b.w;
            #pragma unroll
            for (int d = 1; d < 64; d <<= 1) ss += __shfl_xor(ss, d);
            float scl = (ss > 0.f) ? (1.f / sqrtf(ss)) : 0.f;
            int soff = t * 16384 + m * 1024 + ((lane * 16) ^ ((m & 7) << 4));
            *(bf16x8*)(xb + soff) = pack8s(a, b, scl);
        }
    }
    __syncthreads();
    {
        const float* Wp = tB ? W1 : W0;
        f32x4 acc0 = zero4, acc1 = zero4;
        const unsigned short* Xb = (const unsigned short*)((const char*)&Xbuf[0][0][0] + tB * 16384);
        #pragma unroll
        for (int kc = 0; kc < 16; ++kc) {
            bf16x8 a = ldsAx(Xb, ln, kc * 64 + lg * 16, 1024);
            acc0 = MFMA(a, bfragF(Wp, (size_t)(nq * 32 + ln) * NFEAT + kc * 32 + lg * 8), acc0);
            acc1 = MFMA(a, bfragF(Wp, (size_t)(nq * 32 + 16 + ln) * NFEAT + kc * 32 + lg * 8), acc1);
        }
        unsigned short* Hb = &Hbuf[tB][0][0];
        #pragma unroll
        for (int rg = 0; rg < 4; ++rg) {
            int m = lg * 4 + rg;
            ldsW1(Hb, m, nq * 32 + ln,      f2bf(fmaxf(acc0[rg], 0.f)));
            ldsW1(Hb, m, nq * 32 + 16 + ln, f2bf(fmaxf(acc1[rg], 0.f)));
        }
    }
    __syncthreads();
    {
        const float* Gp = tB ? G2 : G1;
        const unsigned short* Hs = &Hbuf[tB][0][0];
        f32x4 accC[2] = {zero4, zero4};
        #pragma unroll
        for (int kc = 0; kc < 4; ++kc) {
            bf16x8 a = ldsAx(Hs, ln, kc * 64 + lg * 16, 256);
            accC[0] = MFMA(a, bfragF(Gp, (size_t)(nq * 32 + ln) * NHID + kc * 32 + lg * 8), accC[0]);
            accC[1] = MFMA(a, bfragF(Gp, (size_t)(nq * 32 + 16 + ln) * NHID + kc * 32 + lg * 8), accC[1]);
        }
        unsigned short* Gd = G12 + tB * 2048;
        #pragma unroll
        for (int nt = 0; nt < 2; ++nt)
            #pragma unroll
            for (int rg = 0; rg < 4; ++rg) {
                int m = lg * 4 + rg;
                ldsW1(Gd, m, nq * 32 + nt * 16 + ln, f2bf(accC[nt][rg]));
            }
    }
    __syncthreads();
    {
        f32x4 accD = zero4;
        const int n = w * 16 + ln;
        #pragma unroll
        for (int kc = 0; kc < 8; ++kc) {
            const unsigned short* As = G12 + (kc >> 2) * 2048;
            bf16x8 a = ldsAx(As, ln, (kc & 3) * 64 + lg * 16, 256);
            accD = MFMA(a, bfragF(GT, (size_t)n * (2 * NHID) + kc * 32 + lg * 8), accD);
        }
        #pragma unroll
        for (int rg = 0; rg < 4; ++rg) {
            int m = lg * 4 + rg;
            float g  = 1.f / (1.f + __expf(-accD[rg]));
            float h0 = ldsR1(&Hbuf[0][0][0], m, n);
            float h1 = ldsR1(&Hbuf[1][0][0], m, n);
            ldsW1(FIX, m, n, f2bf((1.f - g) * h0 + g * h1));
        }
    }
    __syncthreads();
    if (tid < 256) {
        int r = tid >> 4, sl = tid & 15;
        bf16x8 v = ldsAx(FIX, r, sl * 16, 256);
        float ss = 0.f;
        #pragma unroll
        for (int j = 0; j < 8; ++j) { float f = (float)v[j]; ss += f * f; }
        ss += __shfl_xor(ss, 1); ss += __shfl_xor(ss, 2);
        ss += __shfl_xor(ss, 4); ss += __shfl_xor(ss, 8);
        if (sl == 0) scl2[r] = (ss > 0.f) ? (1.f / sqrtf(ss)) : 0.f;
    }
    __syncthreads();
    if (w < 5) {
        const int cc = w * 16 + ln;
        bf16x8 bfz;
        #pragma unroll
        for (int j = 0; j < 8; ++j) bfz[j] = (__bf16)0.f;
        f32x4 accE = zero4;
        #pragma unroll
        for (int kc = 0; kc < 4; ++kc) {
            bf16x8 a = ldsAx(FIX, ln, kc * 64 + lg * 16, 256);
            bf16x8 b = (cc < NCLASS) ? bfragF(Wc, (size_t)cc * NHID + kc * 32 + lg * 8) : bfz;
            accE = MFMA(a, b, accE);
        }
        #pragma unroll
        for (int rg = 0; rg < 4; ++rg) {
            int m = lg * 4 + rg;
            float v = fmaxf(accE[rg] * scl2[m], 0.f);
            LOG[m * 80 + cc] = (cc < NCLASS) ? v : -1e30f;
        }
    }
    __syncthreads();
    {
        const int r = tid >> 5, l32 = tid & 31;
        float v0 = LOG[r * 80 + l32];
        float v1 = LOG[r * 80 + 32 + l32];
        float v2 = (l32 < 16) ? LOG[r * 80 + 64 + l32] : -1e30f;
        float mx = fmaxf(fmaxf(v0, v1), v2);
        #pragma unroll
        for (int d = 1; d < 32; d <<= 1) mx = fmaxf(mx, __shfl_xor(mx, d, 32));
        float se = __expf(v0 - mx) + __expf(v1 - mx) + ((l32 < 16) ? __expf(v2 - mx) : 0.f);
        #pragma unroll
        for (int d = 1; d < 32; d <<= 1) se += __shfl_xor(se, d, 32);
        float lz = mx + __logf(se);
        size_t orow = (size_t)bid * 16 + r;
        out[orow * NCLASS + l32] = v0 - lz;
        if (l32 + 32 < NCLASS) out[orow * NCLASS + 32 + l32] = v1 - lz;
        if (l32 + 64 < NCLASS) out[orow * NCLASS + 64 + l32] = v2 - lz;
    }
}

extern "C" void kernel_launch(void* const* d_in, const int* in_sizes, int n_in,
                              void* d_out, int out_size, void* d_ws, size_t ws_size,
                              hipStream_t stream)
{
    const float* x   = (const float*)d_in[0];
    const float* sf  = (const float*)d_in[1];
    const int*   idx = (const int*)d_in[2];
    const float* W0  = (const float*)d_in[3];
    const float* W1  = (const float*)d_in[4];
    const float* G1  = (const float*)d_in[5];
    const float* G2  = (const float*)d_in[6];
    const float* GT  = (const float*)d_in[7];
    const float* Wc  = (const float*)d_in[8];
    float* out = (float*)d_out;

    if (ws_size >= WS_NEED) {
        unsigned short* wsH     = (unsigned short*)d_ws;
        unsigned short* wsWimg  = wsH + HELEMS;
        unsigned short* wsSmall = wsWimg + WIMG_ELEMS;
        prep_weights<<<dim3(137), dim3(256), 0, stream>>>(W0, W1, G1, G2, GT, Wc, wsWimg, wsSmall);
        stageB_ws<<<dim3(250), dim3(512), 0, stream>>>(x, sf, idx, wsWimg, wsH);
        tailCDE2<<<dim3(NT2), dim3(512), 0, stream>>>(wsSmall, wsH, out);
    } else {
        hyper_fb<<<dim3(NTILE), dim3(512), 0, stream>>>(
            x, sf, idx, W0, W1, G1, G2, GT, Wc, out);
    }
}

// Round 12
// 36.952 us; speedup vs baseline: 1.3816x; 1.0058x over previous
//
#include <hip/hip_runtime.h>
#include <math.h>

#define NFEAT  512
#define NHID   128
#define NCLASS 70
#define NIDX   10000
#define NTILE  625
#define NT2    313                         // tail blocks: 2 tiles each (last clamped)
#define HELEMS (2u * NIDX * NHID)          // 2,560,000 ushorts: H scratch
#define GELEMS (2u * NIDX * NHID)          // 2,560,000 ushorts: G12 scratch
#define WIMG_ELEMS (2u * 128 * 512)        // 131,072 ushorts: W0/W1 LDS images
#define SMALL_ELEMS 74496u                 // G1,G2,GT,Wc row-major bf16
#define WS_NEED ((size_t)(HELEMS + GELEMS + WIMG_ELEMS + SMALL_ELEMS) * 2)

typedef float  f32x4  __attribute__((ext_vector_type(4)));
typedef __bf16 bf16x8 __attribute__((ext_vector_type(8)));

static __device__ __forceinline__ unsigned short f2bf(float f) {
    unsigned u = __builtin_bit_cast(unsigned, f);
    u += 0x7fffu + ((u >> 16) & 1u);
    return (unsigned short)(u >> 16);
}
static __device__ __forceinline__ float bf2f(unsigned short h) {
    unsigned u = ((unsigned)h) << 16;
    return __builtin_bit_cast(float, u);
}
static __device__ __forceinline__ bf16x8 pack8(float4 a, float4 b) {
    bf16x8 r;
    r[0] = (__bf16)a.x; r[1] = (__bf16)a.y; r[2] = (__bf16)a.z; r[3] = (__bf16)a.w;
    r[4] = (__bf16)b.x; r[5] = (__bf16)b.y; r[6] = (__bf16)b.z; r[7] = (__bf16)b.w;
    return r;
}
static __device__ __forceinline__ bf16x8 pack8s(float4 a, float4 b, float s) {
    bf16x8 r;
    r[0] = (__bf16)(a.x * s); r[1] = (__bf16)(a.y * s); r[2] = (__bf16)(a.z * s); r[3] = (__bf16)(a.w * s);
    r[4] = (__bf16)(b.x * s); r[5] = (__bf16)(b.y * s); r[6] = (__bf16)(b.z * s); r[7] = (__bf16)(b.w * s);
    return r;
}
static __device__ __forceinline__ f32x4 MFMA(bf16x8 a, bf16x8 b, f32x4 c) {
    return __builtin_amdgcn_mfma_f32_16x16x32_bf16(a, b, c, 0, 0, 0);
}
static __device__ __forceinline__ bf16x8 ldsAx(const unsigned short* base, int row, int colb, int rstride) {
    return *(const bf16x8*)((const char*)base + row * rstride + (colb ^ ((row & 7) << 4)));
}
static __device__ __forceinline__ void ldsW1(unsigned short* base, int row, int col, unsigned short v) {
    *(unsigned short*)((char*)base + row * 256 + ((col * 2) ^ ((row & 7) << 4))) = v;
}
static __device__ __forceinline__ float ldsR1(const unsigned short* base, int row, int col) {
    return bf2f(*(const unsigned short*)((const char*)base + row * 256 + ((col * 2) ^ ((row & 7) << 4))));
}

// ---- prep: W0/W1 -> pre-swizzled bf16 LDS images; G1/G2/GT/Wc -> row-major bf16 ----
__global__ void prep_weights(const float* __restrict__ W0, const float* __restrict__ W1,
                             const float* __restrict__ G1, const float* __restrict__ G2,
                             const float* __restrict__ GT, const float* __restrict__ Wc,
                             unsigned short* __restrict__ wsWimg,
                             unsigned short* __restrict__ wsSmall) {
    int i = blockIdx.x * 256 + threadIdx.x;
    if (i < 16384) {
        int t = i >> 13;
        int r = i & 8191;
        int n = r >> 6, k8 = r & 63;
        const float* src = (t ? W1 : W0) + (size_t)n * NFEAT + k8 * 8;
        float4 a = ((const float4*)src)[0], b = ((const float4*)src)[1];
        char* dst = (char*)wsWimg + t * 131072 + n * 1024 + ((k8 * 16) ^ ((n & 7) << 4));
        *(bf16x8*)dst = pack8(a, b);
    } else {
        int i4 = i - 16384;
        if (i4 >= 18624) return;
        const float* src; int base4, dstb;
        if      (i4 < 4096)  { src = G1; base4 = 0;     dstb = 0; }
        else if (i4 < 8192)  { src = G2; base4 = 4096;  dstb = 16384; }
        else if (i4 < 16384) { src = GT; base4 = 8192;  dstb = 32768; }
        else                 { src = Wc; base4 = 16384; dstb = 65536; }
        float4 v = ((const float4*)src)[i4 - base4];
        ushort4 o;
        o.x = f2bf(v.x); o.y = f2bf(v.y); o.z = f2bf(v.z); o.w = f2bf(v.w);
        *(ushort4*)(wsSmall + dstb + (size_t)(i4 - base4) * 4) = o;
    }
}

// ---- stage B+C, weights-stationary: 250 blocks, 5 tiles each ----
// W image in LDS; stage C is tensor-local (gate_t = H_t @ G_t^T) so it fuses here.
__global__ __launch_bounds__(512) void stageBC(
    const float* __restrict__ x, const float* __restrict__ sf,
    const int* __restrict__ idx,
    const unsigned short* __restrict__ wsWimg,
    const unsigned short* __restrict__ wsSmall,
    unsigned short* __restrict__ wsH,
    unsigned short* __restrict__ wsG)
{
    __shared__ __align__(16) unsigned short Wl[65536];  // 128 KB swizzled W image
    __shared__ __align__(16) unsigned short Xl[8192];   // 16 KB swizzled X tile
    __shared__ __align__(16) unsigned short Hl[2048];   // 4 KB swizzled H tile
    __shared__ __align__(16) unsigned short Gl[2048];   // 4 KB swizzled G12 tile

    const int tid  = threadIdx.x;
    const int w    = tid >> 6;
    const int lane = tid & 63;
    const int ln   = lane & 15, lg = lane >> 4;
    const int bid  = blockIdx.x;
    const int t    = bid / 125, tb = bid % 125;
    const int tile0 = tb * 5;
    const float* XS = t ? sf : x;
    const f32x4 zero4 = {0.f, 0.f, 0.f, 0.f};

    // gather volley for tile 0 — longest latency, issue first
    float4 ga0, ga1, gb0, gb1;
    {
        int r0 = idx[tile0 * 16 + w];
        int r1 = idx[tile0 * 16 + w + 8];
        const float4* p0 = (const float4*)(XS + (size_t)r0 * NFEAT + lane * 8);
        const float4* p1 = (const float4*)(XS + (size_t)r1 * NFEAT + lane * 8);
        ga0 = p0[0]; ga1 = p0[1];
        gb0 = p1[0]; gb1 = p1[1];
    }
    // stage-C fragments for this tensor (amortized over 5 tiles)
    bf16x8 cf[4];
    {
        const unsigned short* Gsm = wsSmall + t * 16384;   // G1 or G2 bf16
        #pragma unroll
        for (int kc = 0; kc < 4; ++kc)
            cf[kc] = *(const bf16x8*)(Gsm + (size_t)(w * 16 + ln) * NHID + kc * 32 + lg * 8);
    }
    // W image -> LDS (L2-hot after first blocks)
    {
        const uint4* src = (const uint4*)((const char*)wsWimg + (size_t)t * 131072);
        uint4* dst = (uint4*)Wl;
        #pragma unroll
        for (int i = 0; i < 16; ++i) dst[tid + i * 512] = src[tid + i * 512];
    }
    auto putX = [&](int m, float4 a, float4 b) {
        float ss = a.x*a.x + a.y*a.y + a.z*a.z + a.w*a.w
                 + b.x*b.x + b.y*b.y + b.z*b.z + b.w*b.w;
        #pragma unroll
        for (int d = 1; d < 64; d <<= 1) ss += __shfl_xor(ss, d);
        float scl = (ss > 0.f) ? (1.f / sqrtf(ss)) : 0.f;
        *(bf16x8*)((char*)Xl + m * 1024 + ((lane * 16) ^ ((m & 7) << 4))) = pack8s(a, b, scl);
    };
    putX(w,     ga0, ga1);
    putX(w + 8, gb0, gb1);
    __syncthreads();

    for (int it = 0; it < 5; ++it) {
        // prefetch next tile's gather volley (hides HBM latency under MFMA)
        float4 na0, na1, nb0, nb1;
        if (it < 4) {
            int tile = tile0 + it + 1;
            int r0 = idx[tile * 16 + w];
            int r1 = idx[tile * 16 + w + 8];
            const float4* p0 = (const float4*)(XS + (size_t)r0 * NFEAT + lane * 8);
            const float4* p1 = (const float4*)(XS + (size_t)r1 * NFEAT + lane * 8);
            na0 = p0[0]; na1 = p0[1];
            nb0 = p1[0]; nb1 = p1[1];
        }
        // stage B: wave w -> H cols w*16..w*16+15; both operands from LDS
        f32x4 accE = zero4, accO = zero4;
        #pragma unroll
        for (int kc = 0; kc < 16; ++kc) {
            bf16x8 a = ldsAx(Xl, ln,          kc * 64 + lg * 16, 1024);
            bf16x8 b = ldsAx(Wl, w * 16 + ln, kc * 64 + lg * 16, 1024);
            if (kc & 1) accO = MFMA(a, b, accO); else accE = MFMA(a, b, accE);
        }
        f32x4 acc = accE + accO;
        #pragma unroll
        for (int rg = 0; rg < 4; ++rg)
            ldsW1(Hl, lg * 4 + rg, w * 16 + ln, f2bf(fmaxf(acc[rg], 0.f)));
        __syncthreads();   // b1: Hl ready; Xl reads complete

        // stage C: gate_t = H_t @ G_t^T (4 MFMAs, B from regs)
        f32x4 aC = zero4;
        #pragma unroll
        for (int kc = 0; kc < 4; ++kc) {
            bf16x8 a = ldsAx(Hl, ln, kc * 64 + lg * 16, 256);
            aC = MFMA(a, cf[kc], aC);
        }
        // H tile -> ws; next X tile -> LDS (both overlap stage-C tail)
        if (tid < 256) {
            int tile = tile0 + it;
            ((uint4*)(wsH + ((size_t)t * NIDX + (size_t)tile * 16) * NHID))[tid]
                = ((const uint4*)Hl)[tid];
        }
        if (it < 4) {
            putX(w,     na0, na1);
            putX(w + 8, nb0, nb1);
        }
        #pragma unroll
        for (int rg = 0; rg < 4; ++rg)
            ldsW1(Gl, lg * 4 + rg, w * 16 + ln, f2bf(aC[rg]));
        __syncthreads();   // b2: Gl ready; Xl ready for next iter

        if (tid < 256) {
            int tile = tile0 + it;
            ((uint4*)(wsG + ((size_t)t * NIDX + (size_t)tile * 16) * NHID))[tid]
                = ((const uint4*)Gl)[tid];
        }
    }
}

// ---- tail: stages D/E + softmax over 2 tiles; stage C already done ----
__global__ __launch_bounds__(512) void tailDE2(
    const unsigned short* __restrict__ wsSmall,
    const unsigned short* __restrict__ wsH,
    const unsigned short* __restrict__ wsG,
    float* __restrict__ out)
{
    __shared__ __align__(16) unsigned short Hbuf[2][2][16][NHID]; // 16 KB (tile, tensor)
    __shared__ __align__(16) unsigned short G12s[2][2][16][NHID]; // 16 KB; LOG aliases
    __shared__ __align__(16) unsigned short FIXs[2][16][NHID];    // 8 KB
    __shared__ float scl2[2][16];

    const unsigned short* GTp = wsSmall + 32768;
    const unsigned short* Wcp = wsSmall + 65536;

    const int tid  = threadIdx.x;
    const int bid  = blockIdx.x;
    const int w    = tid >> 6;
    const int lane = tid & 63;
    const int ln   = lane & 15, lg = lane >> 4;
    const f32x4 zero4 = {0.f, 0.f, 0.f, 0.f};
    const int tile0 = bid * 2;
    const int tiles[2] = { tile0, (tile0 + 1 < NTILE) ? tile0 + 1 : NTILE - 1 };

    // --- entry volleys: H + G12 (16 KB each, coalesced), gt, wcf ---
    #pragma unroll
    for (int i = 0; i < 2; ++i) {
        int q = tid + i * 512;             // 0..1023 over [ti][tt][256 uint4]
        int seg = q >> 8, r = q & 255;
        int ti = seg >> 1, tt = seg & 1;
        size_t off = ((size_t)tt * NIDX + (size_t)tiles[ti] * 16) * NHID;
        ((uint4*)&Hbuf[0][0][0][0])[q] = ((const uint4*)(wsH + off))[r];
        ((uint4*)&G12s[0][0][0][0])[q] = ((const uint4*)(wsG + off))[r];
    }
    const int nD = w * 16 + ln;
    bf16x8 gt[8];
    #pragma unroll
    for (int kc = 0; kc < 8; ++kc)
        gt[kc] = *(const bf16x8*)(GTp + (size_t)nD * (2 * NHID) + kc * 32 + lg * 8);
    const int ccE = w * 16 + ln;
    const int ccl = (ccE < NCLASS) ? ccE : 0;
    bf16x8 wcf[4];
    #pragma unroll
    for (int kc = 0; kc < 4; ++kc)
        wcf[kc] = *(const bf16x8*)(Wcp + (size_t)ccl * NHID + kc * 32 + lg * 8);
    __syncthreads();   // b1

    // --- stage D: both tiles ---
    #pragma unroll
    for (int ti = 0; ti < 2; ++ti) {
        f32x4 aE = zero4, aO = zero4;
        #pragma unroll
        for (int kc = 0; kc < 8; ++kc) {
            const unsigned short* As = &G12s[ti][kc >> 2][0][0];
            bf16x8 a = ldsAx(As, ln, (kc & 3) * 64 + lg * 16, 256);
            if (kc & 1) aO = MFMA(a, gt[kc], aO); else aE = MFMA(a, gt[kc], aE);
        }
        f32x4 accD = aE + aO;
        #pragma unroll
        for (int rg = 0; rg < 4; ++rg) {
            int m = lg * 4 + rg;
            float g  = 1.f / (1.f + __expf(-accD[rg]));
            float h0 = ldsR1(&Hbuf[ti][0][0][0], m, nD);
            float h1 = ldsR1(&Hbuf[ti][1][0][0], m, nD);
            ldsW1(&FIXs[ti][0][0], m, nD, f2bf((1.f - g) * h0 + g * h1));
        }
    }
    __syncthreads();   // b2

    // --- fix norms: 512 threads = 32 rows x 16 lanes ---
    {
        int rr = tid >> 4, sl = tid & 15;
        int ti = rr >> 4, r = rr & 15;
        bf16x8 v = ldsAx(&FIXs[ti][0][0], r, sl * 16, 256);
        float ss = 0.f;
        #pragma unroll
        for (int j = 0; j < 8; ++j) { float f = (float)v[j]; ss += f * f; }
        ss += __shfl_xor(ss, 1); ss += __shfl_xor(ss, 2);
        ss += __shfl_xor(ss, 4); ss += __shfl_xor(ss, 8);
        if (sl == 0) scl2[ti][r] = (ss > 0.f) ? (1.f / sqrtf(ss)) : 0.f;
    }
    __syncthreads();   // b3

    // --- stage E: both tiles (waves 0..4); LOG aliases G12s (dead) ---
    if (w < 5) {
        const bool live = (ccE < NCLASS);
        bf16x8 bfz;
        #pragma unroll
        for (int j = 0; j < 8; ++j) bfz[j] = (__bf16)0.f;
        #pragma unroll
        for (int ti = 0; ti < 2; ++ti) {
            f32x4 accE = zero4;
            #pragma unroll
            for (int kc = 0; kc < 4; ++kc) {
                bf16x8 a = ldsAx(&FIXs[ti][0][0], ln, kc * 64 + lg * 16, 256);
                accE = MFMA(a, live ? wcf[kc] : bfz, accE);
            }
            if (live) {
                float* LO = (float*)((char*)&G12s[0][0][0][0] + ti * 8192);
                #pragma unroll
                for (int rg = 0; rg < 4; ++rg) {
                    int m = lg * 4 + rg;
                    LO[m * 80 + ccE] = fmaxf(accE[rg] * scl2[ti][m], 0.f);
                }
            }
        }
    }
    __syncthreads();   // b4

    // --- log_softmax + store: 32 rows x 16 lanes, 5 classes per lane ---
    {
        int rr = tid >> 4, l16 = tid & 15;
        int ti = rr >> 4, r = rr & 15;
        const float* LO = (const float*)((const char*)&G12s[0][0][0][0] + ti * 8192) + r * 80;
        float v[5];
        #pragma unroll
        for (int j = 0; j < 5; ++j) {
            int c = l16 + j * 16;
            v[j] = (c < NCLASS) ? LO[c] : -1e30f;
        }
        float mx = v[0];
        #pragma unroll
        for (int j = 1; j < 5; ++j) mx = fmaxf(mx, v[j]);
        mx = fmaxf(mx, __shfl_xor(mx, 1)); mx = fmaxf(mx, __shfl_xor(mx, 2));
        mx = fmaxf(mx, __shfl_xor(mx, 4)); mx = fmaxf(mx, __shfl_xor(mx, 8));
        float se = 0.f;
        #pragma unroll
        for (int j = 0; j < 5; ++j) {
            int c = l16 + j * 16;
            if (c < NCLASS) se += __expf(v[j] - mx);
        }
        se += __shfl_xor(se, 1); se += __shfl_xor(se, 2);
        se += __shfl_xor(se, 4); se += __shfl_xor(se, 8);
        float lz = mx + __logf(se);
        int tile = tile0 + ti;
        if (tile < NTILE) {
            size_t orow = (size_t)tile * 16 + r;
            #pragma unroll
            for (int j = 0; j < 5; ++j) {
                int c = l16 + j * 16;
                if (c < NCLASS) out[orow * NCLASS + c] = v[j] - lz;
            }
        }
    }
}

// ---- fallback (ws too small): fused kernel, f32 weights inline ----
static __device__ __forceinline__ bf16x8 bfragF(const float* p, size_t off) {
    const float4* q = (const float4*)(p + off);
    return pack8(q[0], q[1]);
}
__global__ __launch_bounds__(512) void hyper_fb(
    const float* __restrict__ x, const float* __restrict__ sf,
    const int* __restrict__ idx,
    const float* __restrict__ W0, const float* __restrict__ W1,
    const float* __restrict__ G1, const float* __restrict__ G2,
    const float* __restrict__ GT, const float* __restrict__ Wc,
    float* __restrict__ out)
{
    __shared__ __align__(16) unsigned short Xbuf[2][16][NFEAT];
    __shared__ __align__(16) unsigned short Hbuf[2][16][NHID];
    __shared__ float scl2[16];
    unsigned short* G12 = &Xbuf[0][0][0];
    unsigned short* FIX = &Xbuf[0][0][0] + 4096;
    float*          LOG = (float*)(&Xbuf[0][0][0] + 6144);

    const int tid = threadIdx.x, bid = blockIdx.x;
    const int w = tid >> 6, lane = tid & 63;
    const int ln = lane & 15, lg = lane >> 4;
    const int tB = w >> 2, nq = w & 3;
    const f32x4 zero4 = {0.f, 0.f, 0.f, 0.f};

    {
        char* xb = (char*)&Xbuf[0][0][0];
        #pragma unroll
        for (int j = 0; j < 4; ++j) {
            int p = w * 4 + j, t = p >> 4, m = p & 15;
            int ri = idx[bid * 16 + m];
            const float4* q = (const float4*)((t ? sf : x) + (size_t)ri * NFEAT + lane * 8);
            float4 a = q[0], b = q[1];
            float ss = a.x*a.x + a.y*a.y + a.z*a.z + a.w*a.w
                     + b.x*b.x + b.y*b.y + b.z*b.z + b.w*b.w;
            #pragma unroll
            for (int d = 1; d < 64; d <<= 1) ss += __shfl_xor(ss, d);
            float scl = (ss > 0.f) ? (1.f / sqrtf(ss)) : 0.f;
            int soff = t * 16384 + m * 1024 + ((lane * 16) ^ ((m & 7) << 4));
            *(bf16x8*)(xb + soff) = pack8s(a, b, scl);
        }
    }
    __syncthreads();
    {
        const float* Wp = tB ? W1 : W0;
        f32x4 acc0 = zero4, acc1 = zero4;
        const unsigned short* Xb = (const unsigned short*)((const char*)&Xbuf[0][0][0] + tB * 16384);
        #pragma unroll
        for (int kc = 0; kc < 16; ++kc) {
            bf16x8 a = ldsAx(Xb, ln, kc * 64 + lg * 16, 1024);
            acc0 = MFMA(a, bfragF(Wp, (size_t)(nq * 32 + ln) * NFEAT + kc * 32 + lg * 8), acc0);
            acc1 = MFMA(a, bfragF(Wp, (size_t)(nq * 32 + 16 + ln) * NFEAT + kc * 32 + lg * 8), acc1);
        }
        unsigned short* Hb = &Hbuf[tB][0][0];
        #pragma unroll
        for (int rg = 0; rg < 4; ++rg) {
            int m = lg * 4 + rg;
            ldsW1(Hb, m, nq * 32 + ln,      f2bf(fmaxf(acc0[rg], 0.f)));
            ldsW1(Hb, m, nq * 32 + 16 + ln, f2bf(fmaxf(acc1[rg], 0.f)));
        }
    }
    __syncthreads();
    {
        const float* Gp = tB ? G2 : G1;
        const unsigned short* Hs = &Hbuf[tB][0][0];
        f32x4 accC[2] = {zero4, zero4};
        #pragma unroll
        for (int kc = 0; kc < 4; ++kc) {
            bf16x8 a = ldsAx(Hs, ln, kc * 64 + lg * 16, 256);
            accC[0] = MFMA(a, bfragF(Gp, (size_t)(nq * 32 + ln) * NHID + kc * 32 + lg * 8), accC[0]);
            accC[1] = MFMA(a, bfragF(Gp, (size_t)(nq * 32 + 16 + ln) * NHID + kc * 32 + lg * 8), accC[1]);
        }
        unsigned short* Gd = G12 + tB * 2048;
        #pragma unroll
        for (int nt = 0; nt < 2; ++nt)
            #pragma unroll
            for (int rg = 0; rg < 4; ++rg) {
                int m = lg * 4 + rg;
                ldsW1(Gd, m, nq * 32 + nt * 16 + ln, f2bf(accC[nt][rg]));
            }
    }
    __syncthreads();
    {
        f32x4 accD = zero4;
        const int n = w * 16 + ln;
        #pragma unroll
        for (int kc = 0; kc < 8; ++kc) {
            const unsigned short* As = G12 + (kc >> 2) * 2048;
            bf16x8 a = ldsAx(As, ln, (kc & 3) * 64 + lg * 16, 256);
            accD = MFMA(a, bfragF(GT, (size_t)n * (2 * NHID) + kc * 32 + lg * 8), accD);
        }
        #pragma unroll
        for (int rg = 0; rg < 4; ++rg) {
            int m = lg * 4 + rg;
            float g  = 1.f / (1.f + __expf(-accD[rg]));
            float h0 = ldsR1(&Hbuf[0][0][0], m, n);
            float h1 = ldsR1(&Hbuf[1][0][0], m, n);
            ldsW1(FIX, m, n, f2bf((1.f - g) * h0 + g * h1));
        }
    }
    __syncthreads();
    if (tid < 256) {
        int r = tid >> 4, sl = tid & 15;
        bf16x8 v = ldsAx(FIX, r, sl * 16, 256);
        float ss = 0.f;
        #pragma unroll
        for (int j = 0; j < 8; ++j) { float f = (float)v[j]; ss += f * f; }
        ss += __shfl_xor(ss, 1); ss += __shfl_xor(ss, 2);
        ss += __shfl_xor(ss, 4); ss += __shfl_xor(ss, 8);
        if (sl == 0) scl2[r] = (ss > 0.f) ? (1.f / sqrtf(ss)) : 0.f;
    }
    __syncthreads();
    if (w < 5) {
        const int cc = w * 16 + ln;
        bf16x8 bfz;
        #pragma unroll
        for (int j = 0; j < 8; ++j) bfz[j] = (__bf16)0.f;
        f32x4 accE = zero4;
        #pragma unroll
        for (int kc = 0; kc < 4; ++kc) {
            bf16x8 a = ldsAx(FIX, ln, kc * 64 + lg * 16, 256);
            bf16x8 b = (cc < NCLASS) ? bfragF(Wc, (size_t)cc * NHID + kc * 32 + lg * 8) : bfz;
            accE = MFMA(a, b, accE);
        }
        #pragma unroll
        for (int rg = 0; rg < 4; ++rg) {
            int m = lg * 4 + rg;
            float v = fmaxf(accE[rg] * scl2[m], 0.f);
            LOG[m * 80 + cc] = (cc < NCLASS) ? v : -1e30f;
        }
    }
    __syncthreads();
    {
        const int r = tid >> 5, l32 = tid & 31;
        float v0 = LOG[r * 80 + l32];
        float v1 = LOG[r * 80 + 32 + l32];
        float v2 = (l32 < 16) ? LOG[r * 80 + 64 + l32] : -1e30f;
        float mx = fmaxf(fmaxf(v0, v1), v2);
        #pragma unroll
        for (int d = 1; d < 32; d <<= 1) mx = fmaxf(mx, __shfl_xor(mx, d, 32));
        float se = __expf(v0 - mx) + __expf(v1 - mx) + ((l32 < 16) ? __expf(v2 - mx) : 0.f);
        #pragma unroll
        for (int d = 1; d < 32; d <<= 1) se += __shfl_xor(se, d, 32);
        float lz = mx + __logf(se);
        size_t orow = (size_t)bid * 16 + r;
        out[orow * NCLASS + l32] = v0 - lz;
        if (l32 + 32 < NCLASS) out[orow * NCLASS + 32 + l32] = v1 - lz;
        if (l32 + 64 < NCLASS) out[orow * NCLASS + 64 + l32] = v2 - lz;
    }
}

extern "C" void kernel_launch(void* const* d_in, const int* in_sizes, int n_in,
                              void* d_out, int out_size, void* d_ws, size_t ws_size,
                              hipStream_t stream)
{
    const float* x   = (const float*)d_in[0];
    const float* sf  = (const float*)d_in[1];
    const int*   idx = (const int*)d_in[2];
    const float* W0  = (const float*)d_in[3];
    const float* W1  = (const float*)d_in[4];
    const float* G1  = (const float*)d_in[5];
    const float* G2  = (const float*)d_in[6];
    const float* GT  = (const float*)d_in[7];
    const float* Wc  = (const float*)d_in[8];
    float* out = (float*)d_out;

    if (ws_size >= WS_NEED) {
        unsigned short* wsH     = (unsigned short*)d_ws;
        unsigned short* wsG     = wsH + HELEMS;
        unsigned short* wsWimg  = wsG + GELEMS;
        unsigned short* wsSmall = wsWimg + WIMG_ELEMS;
        prep_weights<<<dim3(137), dim3(256), 0, stream>>>(W0, W1, G1, G2, GT, Wc, wsWimg, wsSmall);
        stageBC<<<dim3(250), dim3(512), 0, stream>>>(x, sf, idx, wsWimg, wsSmall, wsH, wsG);
        tailDE2<<<dim3(NT2), dim3(512), 0, stream>>>(wsSmall, wsH, wsG, out);
    } else {
        hyper_fb<<<dim3(NTILE), dim3(512), 0, stream>>>(
            x, sf, idx, W0, W1, G1, G2, GT, Wc, out);
    }
}